// Round 2
// baseline (183.630 us; speedup 1.0000x reference)
//
#include <hip/hip_runtime.h>
#include <hip/hip_bf16.h>

#define RR 257
#define RP 288
#define TT 21
#define BPAD 296   // Blds row pitch in shorts (592 B -> 2-way bank alias = free)

typedef __attribute__((ext_vector_type(4))) float f32x4;
typedef __attribute__((ext_vector_type(8))) short bf16x8;

union Pack8 { unsigned short s[8]; uint4 v; };

__device__ __forceinline__ unsigned short f2b(float f) {
    union { float f; unsigned u; } v; v.f = f;
    unsigned r = v.u + 0x7fffu + ((v.u >> 16) & 1u);
    return (unsigned short)(r >> 16);
}

// Stage 1: p{1,2,3}[n,i,r] = concat(layer,1) @ W  (r padded to 288 with zeros), all f32.
__global__ __launch_bounds__(256) void proj_kernel(
    const float* __restrict__ l1, const float* __restrict__ l2, const float* __restrict__ l3,
    const float* __restrict__ W1, const float* __restrict__ W2, const float* __restrict__ W3,
    float* __restrict__ P1f, float* __restrict__ P2f, float* __restrict__ P3f)
{
    int bx = blockIdx.x;           // 3 streams * 4 n * 24 row-groups
    int grp = bx % 24;
    int n = (bx / 24) & 3;
    int s = bx / 96;
    const float* layer = (s == 0) ? l1 : (s == 1) ? l2 : l3;
    const float* W     = (s == 0) ? W1 : (s == 1) ? W2 : W3;
    int i0 = grp * 4;

    __shared__ __attribute__((aligned(16))) float x[2048];  // 4 rows x 512
    const float4* src = (const float4*)(layer + (n * 96 + i0) * 512);
    float4* xv = (float4*)x;
    for (int idx = threadIdx.x; idx < 512; idx += 256) xv[idx] = src[idx];
    __syncthreads();

    for (int r = threadIdx.x; r < RP; r += 256) {
        float a0 = 0.f, a1 = 0.f, a2 = 0.f, a3 = 0.f;
        if (r < RR) {
            float b = W[512 * RR + r];     // bias-ones row
            a0 = a1 = a2 = a3 = b;
            #pragma unroll 8
            for (int a = 0; a < 512; ++a) {
                float wa = W[a * RR + r];
                a0 = fmaf(x[a], wa, a0);
                a1 = fmaf(x[512 + a], wa, a1);
                a2 = fmaf(x[1024 + a], wa, a2);
                a3 = fmaf(x[1536 + a], wa, a3);
            }
        }
        float* P = (s == 0) ? P1f : (s == 1) ? P2f : P3f;
        int base = (n * 96 + i0) * RP + r;
        P[base]          = a0;
        P[base + RP]     = a1;
        P[base + 2 * RP] = a2;
        P[base + 3 * RP] = a3;
    }
}

// Stage 1.5: A'[n][(i*96+j)][r] = p1[n,i,r] * p2[n,j,r], rounded once to bf16.
__global__ __launch_bounds__(256) void aprep_kernel(
    const float* __restrict__ P1f, const float* __restrict__ P2f,
    unsigned short* __restrict__ Ab)
{
    int bx = blockIdx.x;           // 4 n * 96 i
    int n = bx / 96, i = bx % 96;
    __shared__ __attribute__((aligned(16))) float p1row[RP];
    for (int r = threadIdx.x; r < RP; r += 256)
        p1row[r] = P1f[(n * 96 + i) * RP + r];
    __syncthreads();

    unsigned short* dst = Ab + ((size_t)(n * 9216 + i * 96)) * RP;
    for (int idx = threadIdx.x; idx < 96 * 36; idx += 256) {
        int j = idx / 36, c = idx % 36;
        int rb = c * 8;
        const float* p2p = P2f + (n * 96 + j) * RP + rb;
        float4 b0 = *(const float4*)(p2p);
        float4 b1 = *(const float4*)(p2p + 4);
        float4 a0 = *(const float4*)(p1row + rb);
        float4 a1 = *(const float4*)(p1row + rb + 4);
        Pack8 u;
        u.s[0] = f2b(a0.x * b0.x); u.s[1] = f2b(a0.y * b0.y);
        u.s[2] = f2b(a0.z * b0.z); u.s[3] = f2b(a0.w * b0.w);
        u.s[4] = f2b(a1.x * b1.x); u.s[5] = f2b(a1.y * b1.y);
        u.s[6] = f2b(a1.z * b1.z); u.s[7] = f2b(a1.w * b1.w);
        *(uint4*)(dst + (size_t)j * RP + rb) = u.v;
    }
}

// Stage 2: per (n, t, m-tile): C[192, 96] = A'[192,288] * B[96,288]^T.
// B[k][r] = p3[n,k,r] * wl[r,t], formed once in LDS (f32 product, one rounding).
// A-fragments straight from global (L2/L3-hot). No barriers in the K-loop.
__global__ __launch_bounds__(256) void tri2_kernel(
    const unsigned short* __restrict__ Ab, const float* __restrict__ P3f,
    const float* __restrict__ Wl, float* __restrict__ out)
{
    // XCD-aware bijective swizzle: 4032 = 8 * 504; give each XCD a contiguous chunk.
    int orig = blockIdx.x;
    int bx = (orig & 7) * 504 + (orig >> 3);
    int mt = bx % 48;
    int t  = (bx / 48) % TT;
    int n  = bx / (48 * TT);

    __shared__ __attribute__((aligned(16))) unsigned short Blds[96][BPAD];
    __shared__ __attribute__((aligned(16))) float wl_lds[RP];

    int tid = threadIdx.x;
    for (int r = tid; r < RP; r += 256)
        wl_lds[r] = (r < RR) ? Wl[r * TT + t] : 0.f;
    __syncthreads();

    // Form B = p3 (.) wl  -> bf16, 96 x 288, row pitch BPAD.
    for (int idx = tid; idx < 96 * 36; idx += 256) {
        int k = idx / 36, c = idx % 36;
        int rb = c * 8;
        const float* p3p = P3f + (n * 96 + k) * RP + rb;
        float4 p0 = *(const float4*)(p3p);
        float4 p1 = *(const float4*)(p3p + 4);
        float4 w0 = *(const float4*)(wl_lds + rb);
        float4 w1 = *(const float4*)(wl_lds + rb + 4);
        Pack8 u;
        u.s[0] = f2b(p0.x * w0.x); u.s[1] = f2b(p0.y * w0.y);
        u.s[2] = f2b(p0.z * w0.z); u.s[3] = f2b(p0.w * w0.w);
        u.s[4] = f2b(p1.x * w1.x); u.s[5] = f2b(p1.y * w1.y);
        u.s[6] = f2b(p1.z * w1.z); u.s[7] = f2b(p1.w * w1.w);
        *(uint4*)(&Blds[k][rb]) = u.v;
    }
    __syncthreads();

    int lane = tid & 63;
    int wv = tid >> 6;          // 4 waves stacked along M: 48 rows each
    int lrow = lane & 15;
    int lk8 = (lane >> 4) * 8;  // r sub-offset within 32-chunk

    // Per-mf A row pointers (global, bf16, row pitch RP).
    const unsigned short* abase = Ab + ((size_t)n * 9216 + (size_t)mt * 192 + wv * 48) * RP;
    const unsigned short* aptr0 = abase + (0 * 16 + lrow) * RP + lk8;
    const unsigned short* aptr1 = abase + (1 * 16 + lrow) * RP + lk8;
    const unsigned short* aptr2 = abase + (2 * 16 + lrow) * RP + lk8;

    f32x4 acc[3][6] = {};

    #pragma unroll
    for (int ks = 0; ks < 9; ++ks) {
        int r0 = ks * 32;
        bf16x8 af[3], bfr[6];
        af[0] = *(const bf16x8*)(aptr0 + r0);
        af[1] = *(const bf16x8*)(aptr1 + r0);
        af[2] = *(const bf16x8*)(aptr2 + r0);
        #pragma unroll
        for (int nf = 0; nf < 6; ++nf)
            bfr[nf] = *(const bf16x8*)(&Blds[nf * 16 + lrow][r0 + lk8]);
        #pragma unroll
        for (int mf = 0; mf < 3; ++mf)
            #pragma unroll
            for (int nf = 0; nf < 6; ++nf)
                acc[mf][nf] = __builtin_amdgcn_mfma_f32_16x16x32_bf16(
                    af[mf], bfr[nf], acc[mf][nf], 0, 0, 0);
    }

    // Epilogue: C rows are (i,j) pairs -> out tile is one contiguous 192x96 f32 region.
    size_t obase = ((size_t)(n * TT + t) * 9216 + (size_t)mt * 192 + wv * 48) * 96;
    #pragma unroll
    for (int mf = 0; mf < 3; ++mf) {
        int rb = mf * 16 + (lane >> 4) * 4;
        #pragma unroll
        for (int nf = 0; nf < 6; ++nf) {
            int kk = nf * 16 + lrow;
            float* op = out + obase + (size_t)rb * 96 + kk;
            #pragma unroll
            for (int v = 0; v < 4; ++v)
                op[(size_t)v * 96] = acc[mf][nf][v];
        }
    }
}

extern "C" void kernel_launch(void* const* d_in, const int* in_sizes, int n_in,
                              void* d_out, int out_size, void* d_ws, size_t ws_size,
                              hipStream_t stream) {
    const float* l1 = (const float*)d_in[0];
    const float* l2 = (const float*)d_in[1];
    const float* l3 = (const float*)d_in[2];
    const float* W1 = (const float*)d_in[3];
    const float* W2 = (const float*)d_in[4];
    const float* W3 = (const float*)d_in[5];
    const float* Wl = (const float*)d_in[6];

    float* P1f = (float*)d_ws;                 // 384*288*4 B
    float* P2f = P1f + 384 * RP;
    float* P3f = P2f + 384 * RP;
    unsigned short* Ab = (unsigned short*)(P3f + 384 * RP);  // 4*9216*288 bf16 = 21.2 MB

    proj_kernel<<<288, 256, 0, stream>>>(l1, l2, l3, W1, W2, W3, P1f, P2f, P3f);
    aprep_kernel<<<384, 256, 0, stream>>>(P1f, P2f, Ab);
    tri2_kernel<<<4032, 256, 0, stream>>>(Ab, P3f, Wl, (float*)d_out);
}

// Round 3
// 176.150 us; speedup vs baseline: 1.0425x; 1.0425x over previous
//
#include <hip/hip_runtime.h>
#include <hip/hip_bf16.h>

#define RR 257
#define RP 288
#define TT 21

typedef __attribute__((ext_vector_type(4))) float f32x4;
typedef __attribute__((ext_vector_type(8))) short bf16x8;

union Pack8 { unsigned short s[8]; uint4 v; };

__device__ __forceinline__ unsigned short f2b(float f) {
    union { float f; unsigned u; } v; v.f = f;
    unsigned r = v.u + 0x7fffu + ((v.u >> 16) & 1u);
    return (unsigned short)(r >> 16);
}

// Stage 1: p{1,2,3}[n,i,r] = concat(layer,1) @ W  (r padded to 288 with zeros), all f32.
__global__ __launch_bounds__(256) void proj_kernel(
    const float* __restrict__ l1, const float* __restrict__ l2, const float* __restrict__ l3,
    const float* __restrict__ W1, const float* __restrict__ W2, const float* __restrict__ W3,
    float* __restrict__ P1f, float* __restrict__ P2f, float* __restrict__ P3f)
{
    int bx = blockIdx.x;           // 3 streams * 4 n * 24 row-groups
    int grp = bx % 24;
    int n = (bx / 24) & 3;
    int s = bx / 96;
    const float* layer = (s == 0) ? l1 : (s == 1) ? l2 : l3;
    const float* W     = (s == 0) ? W1 : (s == 1) ? W2 : W3;
    int i0 = grp * 4;

    __shared__ __attribute__((aligned(16))) float x[2048];  // 4 rows x 512
    const float4* src = (const float4*)(layer + (n * 96 + i0) * 512);
    float4* xv = (float4*)x;
    for (int idx = threadIdx.x; idx < 512; idx += 256) xv[idx] = src[idx];
    __syncthreads();

    for (int r = threadIdx.x; r < RP; r += 256) {
        float a0 = 0.f, a1 = 0.f, a2 = 0.f, a3 = 0.f;
        if (r < RR) {
            float b = W[512 * RR + r];     // bias-ones row
            a0 = a1 = a2 = a3 = b;
            #pragma unroll 8
            for (int a = 0; a < 512; ++a) {
                float wa = W[a * RR + r];
                a0 = fmaf(x[a], wa, a0);
                a1 = fmaf(x[512 + a], wa, a1);
                a2 = fmaf(x[1024 + a], wa, a2);
                a3 = fmaf(x[1536 + a], wa, a3);
            }
        }
        float* P = (s == 0) ? P1f : (s == 1) ? P2f : P3f;
        int base = (n * 96 + i0) * RP + r;
        P[base]          = a0;
        P[base + RP]     = a1;
        P[base + 2 * RP] = a2;
        P[base + 3 * RP] = a3;
    }
}

// Stage 1.5a: A'[n][(i*96+j)][r] = p1[n,i,r] * p2[n,j,r], rounded once to bf16. 21 MB.
__global__ __launch_bounds__(256) void aprep_kernel(
    const float* __restrict__ P1f, const float* __restrict__ P2f,
    unsigned short* __restrict__ Ab)
{
    int bx = blockIdx.x;           // 4 n * 96 i
    int n = bx / 96, i = bx % 96;
    __shared__ __attribute__((aligned(16))) float p1row[RP];
    for (int r = threadIdx.x; r < RP; r += 256)
        p1row[r] = P1f[(n * 96 + i) * RP + r];
    __syncthreads();

    unsigned short* dst = Ab + ((size_t)(n * 9216 + i * 96)) * RP;
    for (int idx = threadIdx.x; idx < 96 * 36; idx += 256) {
        int j = idx / 36, c = idx % 36;
        int rb = c * 8;
        const float* p2p = P2f + (n * 96 + j) * RP + rb;
        float4 b0 = *(const float4*)(p2p);
        float4 b1 = *(const float4*)(p2p + 4);
        float4 a0 = *(const float4*)(p1row + rb);
        float4 a1 = *(const float4*)(p1row + rb + 4);
        Pack8 u;
        u.s[0] = f2b(a0.x * b0.x); u.s[1] = f2b(a0.y * b0.y);
        u.s[2] = f2b(a0.z * b0.z); u.s[3] = f2b(a0.w * b0.w);
        u.s[4] = f2b(a1.x * b1.x); u.s[5] = f2b(a1.y * b1.y);
        u.s[6] = f2b(a1.z * b1.z); u.s[7] = f2b(a1.w * b1.w);
        *(uint4*)(dst + (size_t)j * RP + rb) = u.v;
    }
}

// Stage 1.5b: B[n][t][k][r] = p3[n,k,r] * wl[r,t], rounded once to bf16. 4.65 MB.
__global__ __launch_bounds__(256) void bprep_kernel(
    const float* __restrict__ P3f, const float* __restrict__ Wl,
    unsigned short* __restrict__ Bb)
{
    int bx = blockIdx.x;           // 4 n * 21 t * 4 k-quarter
    int kq = bx & 3;
    int t  = (bx >> 2) % TT;
    int n  = bx / (4 * TT);

    __shared__ __attribute__((aligned(16))) float wl_lds[RP];
    for (int r = threadIdx.x; r < RP; r += 256)
        wl_lds[r] = (r < RR) ? Wl[r * TT + t] : 0.f;
    __syncthreads();

    unsigned short* dst = Bb + ((size_t)(n * TT + t) * 96 + kq * 24) * RP;
    for (int idx = threadIdx.x; idx < 24 * 36; idx += 256) {
        int k = idx / 36, c = idx % 36;
        int rb = c * 8;
        const float* p3p = P3f + (n * 96 + kq * 24 + k) * RP + rb;
        float4 p0 = *(const float4*)(p3p);
        float4 p1 = *(const float4*)(p3p + 4);
        float4 w0 = *(const float4*)(wl_lds + rb);
        float4 w1 = *(const float4*)(wl_lds + rb + 4);
        Pack8 u;
        u.s[0] = f2b(p0.x * w0.x); u.s[1] = f2b(p0.y * w0.y);
        u.s[2] = f2b(p0.z * w0.z); u.s[3] = f2b(p0.w * w0.w);
        u.s[4] = f2b(p1.x * w1.x); u.s[5] = f2b(p1.y * w1.y);
        u.s[6] = f2b(p1.z * w1.z); u.s[7] = f2b(p1.w * w1.w);
        *(uint4*)(dst + (size_t)k * RP + rb) = u.v;
    }
}

// Stage 2: pure bf16 GEMM, both operands precomputed. Per block (n,t,mt):
// C[96,96] = A'[mt*96..+96, 288] * B_{n,t}[96,288]^T. No LDS, no barriers.
// 4 waves 2x2, each 48x48 (3x3 fragments, 36 acc VGPRs).
__global__ __launch_bounds__(256, 4) void tri3_kernel(
    const unsigned short* __restrict__ Ab, const unsigned short* __restrict__ Bb,
    float* __restrict__ out)
{
    // 8064 blocks = 8 XCDs * 1008; bijective chunked swizzle for L2 locality.
    int orig = blockIdx.x;
    int bx = (orig & 7) * 1008 + (orig >> 3);
    int t = bx % TT;               // t fastest: 21 consecutive blocks reuse one A slab
    int mtn = bx / TT;
    int mt = mtn % 96;
    int n = mtn / 96;

    int tid = threadIdx.x;
    int lane = tid & 63;
    int wv = tid >> 6;
    int wr = wv >> 1, wc = wv & 1;
    int lrow = lane & 15;
    int lk8 = (lane >> 4) * 8;

    const unsigned short* ap = Ab + ((size_t)n * 9216 + mt * 96 + wr * 48 + lrow) * RP + lk8;
    const unsigned short* bp = Bb + ((size_t)(n * TT + t) * 96 + wc * 48 + lrow) * RP + lk8;

    f32x4 acc[3][3] = {};

    #pragma unroll 3
    for (int ks = 0; ks < 9; ++ks) {
        int r0 = ks * 32;
        bf16x8 af[3], bfr[3];
        af[0]  = *(const bf16x8*)(ap + r0);
        af[1]  = *(const bf16x8*)(ap + 16 * RP + r0);
        af[2]  = *(const bf16x8*)(ap + 32 * RP + r0);
        bfr[0] = *(const bf16x8*)(bp + r0);
        bfr[1] = *(const bf16x8*)(bp + 16 * RP + r0);
        bfr[2] = *(const bf16x8*)(bp + 32 * RP + r0);
        #pragma unroll
        for (int mf = 0; mf < 3; ++mf)
            #pragma unroll
            for (int nf = 0; nf < 3; ++nf)
                acc[mf][nf] = __builtin_amdgcn_mfma_f32_16x16x32_bf16(
                    af[mf], bfr[nf], acc[mf][nf], 0, 0, 0);
    }

    // Epilogue: rows (i,j)-pairs are contiguous; nontemporal to keep L2 for A/B.
    size_t obase = ((size_t)(n * TT + t) * 9216 + mt * 96 + wr * 48) * 96 + wc * 48;
    #pragma unroll
    for (int mf = 0; mf < 3; ++mf) {
        int rb = mf * 16 + (lane >> 4) * 4;
        #pragma unroll
        for (int nf = 0; nf < 3; ++nf) {
            int kk = nf * 16 + lrow;
            float* op = out + obase + (size_t)rb * 96 + kk;
            #pragma unroll
            for (int v = 0; v < 4; ++v)
                __builtin_nontemporal_store(acc[mf][nf][v], op + (size_t)v * 96);
        }
    }
}

extern "C" void kernel_launch(void* const* d_in, const int* in_sizes, int n_in,
                              void* d_out, int out_size, void* d_ws, size_t ws_size,
                              hipStream_t stream) {
    const float* l1 = (const float*)d_in[0];
    const float* l2 = (const float*)d_in[1];
    const float* l3 = (const float*)d_in[2];
    const float* W1 = (const float*)d_in[3];
    const float* W2 = (const float*)d_in[4];
    const float* W3 = (const float*)d_in[5];
    const float* Wl = (const float*)d_in[6];

    float* P1f = (float*)d_ws;                 // 3 x 384*288 f32
    float* P2f = P1f + 384 * RP;
    float* P3f = P2f + 384 * RP;
    unsigned short* Ab = (unsigned short*)(P3f + 384 * RP);  // 4*9216*288 bf16 = 21.2 MB
    unsigned short* Bb = Ab + (size_t)4 * 9216 * RP;         // 4*21*96*288 bf16 = 4.65 MB

    proj_kernel<<<288, 256, 0, stream>>>(l1, l2, l3, W1, W2, W3, P1f, P2f, P3f);
    aprep_kernel<<<384, 256, 0, stream>>>(P1f, P2f, Ab);
    bprep_kernel<<<336, 256, 0, stream>>>(P3f, Wl, Bb);
    tri3_kernel<<<8064, 256, 0, stream>>>(Ab, Bb, (float*)d_out);
}

// Round 4
// 116.639 us; speedup vs baseline: 1.5743x; 1.5102x over previous
//
#include <hip/hip_runtime.h>
#include <hip/hip_bf16.h>

#define RR 257
#define RP 288
#define TT 21

typedef __attribute__((ext_vector_type(4))) float f32x4;
typedef __attribute__((ext_vector_type(8))) short bf16x8;

union Pack8 { unsigned short s[8]; uint4 v; };

__device__ __forceinline__ unsigned short f2b(float f) {
    union { float f; unsigned u; } v; v.f = f;
    unsigned r = v.u + 0x7fffu + ((v.u >> 16) & 1u);
    return (unsigned short)(r >> 16);
}

// Stage 1: p{1,2,3}[n,i,r] = concat(layer,1) @ W  (r padded to 288 with zeros), f32.
__global__ __launch_bounds__(384) void proj_kernel(
    const float* __restrict__ l1, const float* __restrict__ l2, const float* __restrict__ l3,
    const float* __restrict__ W1, const float* __restrict__ W2, const float* __restrict__ W3,
    float* __restrict__ P1f, float* __restrict__ P2f, float* __restrict__ P3f)
{
    int bx = blockIdx.x;           // 3 streams * 4 n * 24 row-groups (4 rows each)
    int grp = bx % 24;
    int n = (bx / 24) & 3;
    int s = bx / 96;
    const float* layer = (s == 0) ? l1 : (s == 1) ? l2 : l3;
    const float* W     = (s == 0) ? W1 : (s == 1) ? W2 : W3;
    int i0 = grp * 4;

    __shared__ __attribute__((aligned(16))) float x[2048];  // 4 rows x 512
    const float4* src = (const float4*)(layer + (n * 96 + i0) * 512);
    float4* xv = (float4*)x;
    for (int idx = threadIdx.x; idx < 512; idx += 384) xv[idx] = src[idx];
    __syncthreads();

    int r = threadIdx.x;
    if (r < RP) {
        float a0 = 0.f, a1 = 0.f, a2 = 0.f, a3 = 0.f;
        if (r < RR) {
            float b = W[512 * RR + r];     // bias-ones row
            a0 = a1 = a2 = a3 = b;
            #pragma unroll 8
            for (int a = 0; a < 512; ++a) {
                float wa = W[a * RR + r];
                a0 = fmaf(x[a], wa, a0);
                a1 = fmaf(x[512 + a], wa, a1);
                a2 = fmaf(x[1024 + a], wa, a2);
                a3 = fmaf(x[1536 + a], wa, a3);
            }
        }
        float* P = (s == 0) ? P1f : (s == 1) ? P2f : P3f;
        int base = (n * 96 + i0) * RP + r;
        P[base]          = a0;
        P[base + RP]     = a1;
        P[base + 2 * RP] = a2;
        P[base + 3 * RP] = a3;
    }
}

// Stage 1.5a: A'[m=(i,j)][r] = p1[i,r]*p2[j,r] -> bf16, stored FRAGMENT-ORDERED:
// Af[((n*576 + rg)*9 + ks)*512 + L*8 + e] = A'[rg*16 + (L&15)][ks*32 + (L>>4)*8 + e]
__global__ __launch_bounds__(256) void aprep_kernel(
    const float* __restrict__ P1f, const float* __restrict__ P2f,
    unsigned short* __restrict__ Af)
{
    int bx = blockIdx.x;           // 4 n * 96 i
    int n = bx / 96, i = bx % 96;
    __shared__ __attribute__((aligned(16))) float p1row[RP];
    for (int r = threadIdx.x; r < RP; r += 256)
        p1row[r] = P1f[(n * 96 + i) * RP + r];
    __syncthreads();

    unsigned short* dst = Af + (size_t)(n * 576 + i * 6) * 9 * 512;
    for (int idx = threadIdx.x; idx < 3456; idx += 256) {
        int L = idx & 63;
        int rest = idx >> 6;            // 0..53
        int ks = rest % 9, rgl = rest / 9;
        int j = rgl * 16 + (L & 15);
        int k8 = ks * 32 + (L >> 4) * 8;
        const float* p2p = P2f + (n * 96 + j) * RP + k8;
        float4 b0 = *(const float4*)(p2p);
        float4 b1 = *(const float4*)(p2p + 4);
        float4 a0 = *(const float4*)(p1row + k8);
        float4 a1 = *(const float4*)(p1row + k8 + 4);
        Pack8 u;
        u.s[0] = f2b(a0.x * b0.x); u.s[1] = f2b(a0.y * b0.y);
        u.s[2] = f2b(a0.z * b0.z); u.s[3] = f2b(a0.w * b0.w);
        u.s[4] = f2b(a1.x * b1.x); u.s[5] = f2b(a1.y * b1.y);
        u.s[6] = f2b(a1.z * b1.z); u.s[7] = f2b(a1.w * b1.w);
        *(uint4*)(dst + (size_t)(rgl * 9 + ks) * 512 + L * 8) = u.v;
    }
}

// Stage 1.5b: B[k][r] = p3[k,r]*wl[r,t] -> bf16, fragment-ordered:
// Bf[(((n*21+t)*6 + kg)*9 + ks)*512 + L*8 + e] = B[kg*16 + (L&15)][ks*32 + (L>>4)*8 + e]
__global__ __launch_bounds__(256) void bprep_kernel(
    const float* __restrict__ P3f, const float* __restrict__ Wl,
    unsigned short* __restrict__ Bf)
{
    int bx = blockIdx.x;           // 4 n * 21 t
    int t = bx % TT, n = bx / TT;
    __shared__ __attribute__((aligned(16))) float wl_lds[RP];
    for (int r = threadIdx.x; r < RP; r += 256)
        wl_lds[r] = (r < RR) ? Wl[r * TT + t] : 0.f;
    __syncthreads();

    unsigned short* dst = Bf + (size_t)(n * TT + t) * 6 * 9 * 512;
    for (int idx = threadIdx.x; idx < 3456; idx += 256) {
        int L = idx & 63;
        int rest = idx >> 6;
        int ks = rest % 9, kg = rest / 9;
        int col = kg * 16 + (L & 15);
        int r8 = ks * 32 + (L >> 4) * 8;
        const float* p3p = P3f + (n * 96 + col) * RP + r8;
        float4 p0 = *(const float4*)(p3p);
        float4 p1 = *(const float4*)(p3p + 4);
        float4 w0 = *(const float4*)(wl_lds + r8);
        float4 w1 = *(const float4*)(wl_lds + r8 + 4);
        Pack8 u;
        u.s[0] = f2b(p0.x * w0.x); u.s[1] = f2b(p0.y * w0.y);
        u.s[2] = f2b(p0.z * w0.z); u.s[3] = f2b(p0.w * w0.w);
        u.s[4] = f2b(p1.x * w1.x); u.s[5] = f2b(p1.y * w1.y);
        u.s[6] = f2b(p1.z * w1.z); u.s[7] = f2b(p1.w * w1.w);
        *(uint4*)(dst + (size_t)(kg * 9 + ks) * 512 + L * 8) = u.v;
    }
}

#define LOADA(s, kss) { _Pragma("unroll") for (int mf = 0; mf < 4; ++mf) \
    fa[s][mf] = *(const bf16x8*)(abase + (mf * 9 + (kss)) * 512); }
#define LOADB(s, kss) { _Pragma("unroll") for (int nf = 0; nf < 6; ++nf) \
    fb[s][nf] = *(const bf16x8*)(bbase + (nf * 9 + (kss)) * 512); }
#define MFMAS(s) { _Pragma("unroll") for (int mf = 0; mf < 4; ++mf) { \
    _Pragma("unroll") for (int nf = 0; nf < 6; ++nf) \
      acc[mf][nf] = __builtin_amdgcn_mfma_f32_16x16x32_bf16(fb[s][nf], fa[s][mf], acc[mf][nf], 0, 0, 0); } }

// Stage 2: per block (n,t,mt): C[256,96] = A'[256,288] * B[96,288]^T.
// All fragment loads are base+lane*16 (fully coalesced 1KB/wave). No LDS in K-loop.
// Computes C^T fragments (swapped mfma args) so each lane holds 4 consecutive k
// -> LDS transpose -> fully coalesced float4 NT stores (full 128B lines).
__global__ __launch_bounds__(256, 2) void tri4_kernel(
    const unsigned short* __restrict__ Af, const unsigned short* __restrict__ Bf,
    float* __restrict__ out)
{
    // 3024 blocks = 8 XCDs * 378; bijective chunked swizzle; t fastest (A-slab reuse).
    int orig = blockIdx.x;
    int bx = (orig & 7) * 378 + (orig >> 3);
    int t = bx % TT;
    int mtn = bx / TT;
    int mt = mtn % 36;
    int n = mtn / 36;

    int tid = threadIdx.x, lane = tid & 63, wv = tid >> 6;

    const unsigned short* abase = Af + (size_t)(n * 576 + mt * 16 + wv * 4) * 9 * 512 + lane * 8;
    const unsigned short* bbase = Bf + (size_t)(n * TT + t) * 6 * 9 * 512 + lane * 8;

    f32x4 acc[4][6] = {};
    bf16x8 fa[2][4], fb[2][6];

    LOADA(0, 0); LOADB(0, 0);
    #pragma unroll
    for (int kp = 0; kp < 4; ++kp) {
        LOADA(1, 2 * kp + 1); LOADB(1, 2 * kp + 1);
        MFMAS(0);
        LOADA(0, 2 * kp + 2); LOADB(0, 2 * kp + 2);
        MFMAS(1);
    }
    MFMAS(0);   // ks = 8

    // Epilogue: per-wave LDS transpose (pitch 100 f32 -> conflict-free), then
    // contiguous float4 NT stores: each wave-store = 1KB = 8 full lines.
    __shared__ __attribute__((aligned(16))) float tbuf[4][1600];
    int Llo = lane & 15, Lhi = lane >> 4;
    size_t outbase = ((size_t)(n * TT + t) * 9216 + mt * 256 + wv * 64) * 96;

    #pragma unroll
    for (int mf = 0; mf < 4; ++mf) {
        #pragma unroll
        for (int nf = 0; nf < 6; ++nf)
            *(f32x4*)&tbuf[wv][Llo * 100 + nf * 16 + Lhi * 4] = acc[mf][nf];
        float* gdst = out + outbase + (size_t)mf * 16 * 96;
        #pragma unroll
        for (int q = 0; q < 6; ++q) {
            int fidx = q * 64 + lane;
            int ml = fidx / 24, k4 = fidx % 24;
            f32x4 vv = *(const f32x4*)&tbuf[wv][ml * 100 + k4 * 4];
            __builtin_nontemporal_store(vv, (f32x4*)(gdst + (size_t)fidx * 4));
        }
    }
}

extern "C" void kernel_launch(void* const* d_in, const int* in_sizes, int n_in,
                              void* d_out, int out_size, void* d_ws, size_t ws_size,
                              hipStream_t stream) {
    const float* l1 = (const float*)d_in[0];
    const float* l2 = (const float*)d_in[1];
    const float* l3 = (const float*)d_in[2];
    const float* W1 = (const float*)d_in[3];
    const float* W2 = (const float*)d_in[4];
    const float* W3 = (const float*)d_in[5];
    const float* Wl = (const float*)d_in[6];

    float* P1f = (float*)d_ws;                 // 3 x 384*288 f32
    float* P2f = P1f + 384 * RP;
    float* P3f = P2f + 384 * RP;
    unsigned short* Af = (unsigned short*)(P3f + 384 * RP);  // 4*576*9*512 bf16 = 21.2 MB
    unsigned short* Bf = Af + (size_t)4 * 576 * 9 * 512;     // 4*21*6*9*512 bf16 = 4.65 MB

    proj_kernel<<<288, 384, 0, stream>>>(l1, l2, l3, W1, W2, W3, P1f, P2f, P3f);
    aprep_kernel<<<384, 256, 0, stream>>>(P1f, P2f, Af);
    bprep_kernel<<<84, 256, 0, stream>>>(P3f, Wl, Bf);
    tri4_kernel<<<3024, 256, 0, stream>>>(Af, Bf, (float*)d_out);
}